// Round 1
// baseline (374.324 us; speedup 1.0000x reference)
//
#include <hip/hip_runtime.h>

// Problem constants (fixed by the reference harness)
constexpr int B = 32;
constexpr int T = 4096;   // frames
constexpr int P = 512;    // phonemes
constexpr int H = 512;    // hidden
constexpr int H4 = H / 4; // 128 float4 per row
constexpr int LOG2_H4 = 7;
constexpr int LOG2_T = 12;

// ---------------------------------------------------------------------------
// Kernel 1: per-batch inclusive prefix sum of change flags -> idx[B*T]
// One block per batch row. 256 threads x 16 elements each.
// ---------------------------------------------------------------------------
__global__ __launch_bounds__(256) void scan_idx_kernel(
    const int* __restrict__ align, int* __restrict__ idx) {
  const int b = blockIdx.x;
  const int tid = threadIdx.x;
  const long base = (long)b * T;
  constexpr int CH = T / 256; // 16
  const int start = tid * CH;

  int local[CH];
  // previous element (for start==0 the flag at j==0 is forced to 0 anyway)
  int prev = align[base + (start > 0 ? start - 1 : 0)];
  int run = 0;
#pragma unroll
  for (int j = 0; j < CH; ++j) {
    int a = align[base + start + j];
    run += ((start + j) > 0 && a != prev) ? 1 : 0;
    prev = a;
    local[j] = run;
  }

  __shared__ int sums[256];
  sums[tid] = run;
  __syncthreads();
  // Hillis-Steele inclusive scan over 256 per-thread totals
  for (int off = 1; off < 256; off <<= 1) {
    int v = (tid >= off) ? sums[tid - off] : 0;
    __syncthreads();
    sums[tid] += v;
    __syncthreads();
  }
  const int excl = (tid > 0) ? sums[tid - 1] : 0;

#pragma unroll
  for (int j = 0; j < CH; ++j) {
    int v = excl + local[j];
    idx[base + start + j] = (v > (P - 1)) ? (P - 1) : v;
  }
}

// ---------------------------------------------------------------------------
// Kernel 2: out[b,t,h] = enc[b, idx[b,t], h]
//                      + pitch[b,t]*w_pitch[h] + b_pitch[h]
//                      + beats[b,t]*w_beats[h] + b_beats[h]
//                      + t*w_pos[h] + b_pos[h]
// Grid-stride over float4 elements; weights stay L1-resident.
// ---------------------------------------------------------------------------
__global__ __launch_bounds__(256) void fuse_kernel(
    const float4* __restrict__ enc,    // [B, P, H4]
    const float* __restrict__ pitch,   // [B*T]
    const float* __restrict__ beats,   // [B*T]
    const float4* __restrict__ wp, const float4* __restrict__ bp,
    const float4* __restrict__ wb, const float4* __restrict__ bb,
    const float4* __restrict__ wpos, const float4* __restrict__ bpos,
    const int* __restrict__ idx,       // [B*T]
    float4* __restrict__ out) {        // [B*T, H4]
  const long total4 = (long)B * T * H4;
  long i = (long)blockIdx.x * blockDim.x + threadIdx.x;
  const long stride = (long)gridDim.x * blockDim.x;

  for (; i < total4; i += stride) {
    const int col = (int)(i & (H4 - 1));
    const long row = i >> LOG2_H4;          // b*T + t
    const int t = (int)(row & (T - 1));
    const int b = (int)(row >> LOG2_T);

    const int e = idx[row];
    const float p = pitch[row];
    const float q = beats[row];
    const float tf = (float)t;

    const float4 ev = enc[((long)(b * P + e) << LOG2_H4) + col];
    const float4 w1 = wp[col], c1 = bp[col];
    const float4 w2 = wb[col], c2 = bb[col];
    const float4 w3 = wpos[col], c3 = bpos[col];

    float4 o;
    o.x = ev.x + fmaf(p, w1.x, c1.x) + fmaf(q, w2.x, c2.x) + fmaf(tf, w3.x, c3.x);
    o.y = ev.y + fmaf(p, w1.y, c1.y) + fmaf(q, w2.y, c2.y) + fmaf(tf, w3.y, c3.y);
    o.z = ev.z + fmaf(p, w1.z, c1.z) + fmaf(q, w2.z, c2.z) + fmaf(tf, w3.z, c3.z);
    o.w = ev.w + fmaf(p, w1.w, c1.w) + fmaf(q, w2.w, c2.w) + fmaf(tf, w3.w, c3.w);
    out[i] = o;
  }
}

extern "C" void kernel_launch(void* const* d_in, const int* in_sizes, int n_in,
                              void* d_out, int out_size, void* d_ws, size_t ws_size,
                              hipStream_t stream) {
  const float* enc     = (const float*)d_in[0]; // [B,P,H]
  const float* pitch   = (const float*)d_in[1]; // [B,T]
  const float* beats   = (const float*)d_in[2]; // [B,T]
  const float* w_pitch = (const float*)d_in[3];
  const float* b_pitch = (const float*)d_in[4];
  const float* w_beats = (const float*)d_in[5];
  const float* b_beats = (const float*)d_in[6];
  const float* w_pos   = (const float*)d_in[7];
  const float* b_pos   = (const float*)d_in[8];
  const int* align     = (const int*)d_in[9];   // [B,T]

  int* idx = (int*)d_ws; // B*T ints = 512 KB scratch

  scan_idx_kernel<<<B, 256, 0, stream>>>(align, idx);

  const long total4 = (long)B * T * H4; // 16,777,216
  const int block = 256;
  const int grid = 2048; // grid-stride; 256 CUs x 8 blocks
  fuse_kernel<<<grid, block, 0, stream>>>(
      (const float4*)enc, pitch, beats,
      (const float4*)w_pitch, (const float4*)b_pitch,
      (const float4*)w_beats, (const float4*)b_beats,
      (const float4*)w_pos, (const float4*)b_pos,
      idx, (float4*)d_out);
  (void)in_sizes; (void)n_in; (void)out_size; (void)ws_size; (void)total4;
}

// Round 4
// 329.288 us; speedup vs baseline: 1.1368x; 1.1368x over previous
//
#include <hip/hip_runtime.h>

// Problem constants (fixed by the reference harness)
constexpr int B = 32;
constexpr int T = 4096;   // frames
constexpr int P = 512;    // phonemes
constexpr int H = 512;    // hidden
constexpr int H4 = H / 4; // 128 float4 per row
constexpr int LOG2_H4 = 7;

// ---------------------------------------------------------------------------
// Kernel 1: per-batch inclusive prefix sum of change flags -> packed row data
// packed[row] = { __int_as_float((b*P + idx)*128), pitch[row], beats[row], (float)t }
// One block per batch row. 256 threads x 16 elements each.
// ---------------------------------------------------------------------------
__global__ __launch_bounds__(256) void scan_idx_kernel(
    const int* __restrict__ align,
    const float* __restrict__ pitch,
    const float* __restrict__ beats,
    float4* __restrict__ packed) {
  const int b = blockIdx.x;
  const int tid = threadIdx.x;
  const long base = (long)b * T;
  constexpr int CH = T / 256; // 16
  const int start = tid * CH;

  int local[CH];
  int prev = align[base + (start > 0 ? start - 1 : 0)];
  int run = 0;
#pragma unroll
  for (int j = 0; j < CH; ++j) {
    int a = align[base + start + j];
    run += ((start + j) > 0 && a != prev) ? 1 : 0;
    prev = a;
    local[j] = run;
  }

  __shared__ int sums[256];
  sums[tid] = run;
  __syncthreads();
  for (int off = 1; off < 256; off <<= 1) {
    int v = (tid >= off) ? sums[tid - off] : 0;
    __syncthreads();
    sums[tid] += v;
    __syncthreads();
  }
  const int excl = (tid > 0) ? sums[tid - 1] : 0;

#pragma unroll
  for (int j = 0; j < CH; ++j) {
    int v = excl + local[j];
    v = (v > (P - 1)) ? (P - 1) : v;
    float4 pk;
    pk.x = __int_as_float((b * P + v) << LOG2_H4); // enc float4-base for this row
    pk.y = pitch[base + start + j];
    pk.z = beats[base + start + j];
    pk.w = (float)(start + j);                     // t
    packed[base + start + j] = pk;
  }
}

// ---------------------------------------------------------------------------
// Kernel 2: out[row, col] = enc[ebase + col] + p*w1 + q*w2 + tf*w3 + (c1+c2+c3)
// Fixed col per thread: weights/biases hoisted out of the row loop.
// 3 VMEM per 16B of output (uniform packed load, enc load, store).
// XCD swizzle: each of 8 XCDs owns 4 contiguous batches -> 4 MB enc slice
// stays resident in its private L2.
// ---------------------------------------------------------------------------
__global__ __launch_bounds__(256) void fuse_kernel(
    const float4* __restrict__ enc,     // [B*P, H4]
    const float4* __restrict__ packed,  // [B*T]
    const float4* __restrict__ wp, const float4* __restrict__ bp,
    const float4* __restrict__ wb, const float4* __restrict__ bb,
    const float4* __restrict__ wpos, const float4* __restrict__ bpos,
    float4* __restrict__ out) {         // [B*T, H4]
  const int tid = threadIdx.x;
  const int col = tid & (H4 - 1);
  const int rowHalf = tid >> 7; // 0 or 1: block covers 2 rows per iteration

  // Hoisted weights; biases pre-summed.
  const float4 w1 = wp[col], w2 = wb[col], w3 = wpos[col];
  float4 cs;
  {
    const float4 c1 = bp[col], c2 = bb[col], c3 = bpos[col];
    cs.x = c1.x + c2.x + c3.x;
    cs.y = c1.y + c2.y + c3.y;
    cs.z = c1.z + c2.z + c3.z;
    cs.w = c1.w + c2.w + c3.w;
  }

  // XCD-contiguous row assignment: 2048 blocks = 8 XCDs x 256 blocks.
  const int bid = blockIdx.x;
  const int xcd = bid & 7;       // assumes round-robin block->XCD (perf only)
  const int lb = bid >> 3;       // 0..255 within XCD
  constexpr int ROWS_PER_XCD = (B * T) / 8; // 16384 rows = 4 batches
  int r = xcd * ROWS_PER_XCD + lb * 2 + rowHalf;
  const int rEnd = xcd * ROWS_PER_XCD + ROWS_PER_XCD;

  for (; r < rEnd; r += 512) {
    const int rU = __builtin_amdgcn_readfirstlane(r);
    const float4 pk = packed[rU];          // wave-uniform 16B broadcast
    const int ebase = __float_as_int(pk.x);
    const float4 ev = enc[ebase + col];

    float4 o;
    o.x = ev.x + fmaf(pk.y, w1.x, fmaf(pk.z, w2.x, fmaf(pk.w, w3.x, cs.x)));
    o.y = ev.y + fmaf(pk.y, w1.y, fmaf(pk.z, w2.y, fmaf(pk.w, w3.y, cs.y)));
    o.z = ev.z + fmaf(pk.y, w1.z, fmaf(pk.z, w2.z, fmaf(pk.w, w3.z, cs.z)));
    o.w = ev.w + fmaf(pk.y, w1.w, fmaf(pk.z, w2.w, fmaf(pk.w, w3.w, cs.w)));

    out[((long)r << LOG2_H4) + col] = o;
  }
}

extern "C" void kernel_launch(void* const* d_in, const int* in_sizes, int n_in,
                              void* d_out, int out_size, void* d_ws, size_t ws_size,
                              hipStream_t stream) {
  const float* enc     = (const float*)d_in[0]; // [B,P,H]
  const float* pitch   = (const float*)d_in[1]; // [B,T]
  const float* beats   = (const float*)d_in[2]; // [B,T]
  const float* w_pitch = (const float*)d_in[3];
  const float* b_pitch = (const float*)d_in[4];
  const float* w_beats = (const float*)d_in[5];
  const float* b_beats = (const float*)d_in[6];
  const float* w_pos   = (const float*)d_in[7];
  const float* b_pos   = (const float*)d_in[8];
  const int* align     = (const int*)d_in[9];   // [B,T]

  float4* packed = (float4*)d_ws; // B*T float4 = 2 MB scratch

  scan_idx_kernel<<<B, 256, 0, stream>>>(align, pitch, beats, packed);

  fuse_kernel<<<2048, 256, 0, stream>>>(
      (const float4*)enc, packed,
      (const float4*)w_pitch, (const float4*)b_pitch,
      (const float4*)w_beats, (const float4*)b_beats,
      (const float4*)w_pos, (const float4*)b_pos,
      (float4*)d_out);
  (void)in_sizes; (void)n_in; (void)out_size; (void)ws_size;
}

// Round 5
// 317.837 us; speedup vs baseline: 1.1777x; 1.0360x over previous
//
#include <hip/hip_runtime.h>

// Problem constants (fixed by the reference harness)
constexpr int B = 32;
constexpr int T = 4096;   // frames
constexpr int P = 512;    // phonemes
constexpr int H = 512;    // hidden
constexpr int H4 = H / 4; // 128 float4 per row
constexpr int LOG2_H4 = 7;

using f32x4 = __attribute__((ext_vector_type(4))) float;

// ---------------------------------------------------------------------------
// Kernel 1: per-batch inclusive prefix sum of change flags -> packed row data
// packed[row] = { bitcast(enc float4-base), pitch[row], beats[row], (float)t }
// ---------------------------------------------------------------------------
__global__ __launch_bounds__(256) void scan_idx_kernel(
    const int* __restrict__ align,
    const float* __restrict__ pitch,
    const float* __restrict__ beats,
    f32x4* __restrict__ packed) {
  const int b = blockIdx.x;
  const int tid = threadIdx.x;
  const long base = (long)b * T;
  constexpr int CH = T / 256; // 16
  const int start = tid * CH;

  int local[CH];
  int prev = align[base + (start > 0 ? start - 1 : 0)];
  int run = 0;
#pragma unroll
  for (int j = 0; j < CH; ++j) {
    int a = align[base + start + j];
    run += ((start + j) > 0 && a != prev) ? 1 : 0;
    prev = a;
    local[j] = run;
  }

  __shared__ int sums[256];
  sums[tid] = run;
  __syncthreads();
  for (int off = 1; off < 256; off <<= 1) {
    int v = (tid >= off) ? sums[tid - off] : 0;
    __syncthreads();
    sums[tid] += v;
    __syncthreads();
  }
  const int excl = (tid > 0) ? sums[tid - 1] : 0;

#pragma unroll
  for (int j = 0; j < CH; ++j) {
    int v = excl + local[j];
    v = (v > (P - 1)) ? (P - 1) : v;
    f32x4 pk;
    pk.x = __int_as_float((b * P + v) << LOG2_H4); // enc float4-base
    pk.y = pitch[base + start + j];
    pk.z = beats[base + start + j];
    pk.w = (float)(start + j);                     // t
    packed[base + start + j] = pk;
  }
}

// ---------------------------------------------------------------------------
// Kernel 2: block bid owns 64 CONSECUTIVE rows [bid*64, bid*64+64).
//  - monotone gather within block (idx sorted per batch) -> enc row L1-hits
//  - contiguous 128 KB output segment per block
//  - non-temporal stores: keep the 256 MB out-stream from evicting enc in L2
//  - 2 independent rows in flight per iteration (ILP)
// ---------------------------------------------------------------------------
__global__ __launch_bounds__(256) void fuse_kernel(
    const f32x4* __restrict__ enc,     // [B*P, H4]
    const f32x4* __restrict__ packed,  // [B*T]
    const f32x4* __restrict__ wp, const f32x4* __restrict__ bp,
    const f32x4* __restrict__ wb, const f32x4* __restrict__ bb,
    const f32x4* __restrict__ wpos, const f32x4* __restrict__ bpos,
    f32x4* __restrict__ out) {         // [B*T, H4]
  const int tid = threadIdx.x;
  const int col = tid & (H4 - 1);
  const int rowHalf = tid >> 7; // 0 or 1

  // Hoisted weights; biases pre-summed.
  const f32x4 w1 = wp[col], w2 = wb[col], w3 = wpos[col];
  const f32x4 cs = bp[col] + bb[col] + bpos[col];

  const int base = blockIdx.x * 64;

#pragma unroll 4
  for (int i = 0; i < 16; ++i) {
    const int ra = base + i * 4 + rowHalf;     // rows {base+4i, base+4i+1}
    const int rb = ra + 2;                     // rows {base+4i+2, base+4i+3}
    const int raU = __builtin_amdgcn_readfirstlane(ra);
    const int rbU = __builtin_amdgcn_readfirstlane(rb);
    const f32x4 pka = packed[raU];             // wave-uniform broadcast
    const f32x4 pkb = packed[rbU];
    const f32x4 eva = enc[__float_as_int(pka.x) + col];
    const f32x4 evb = enc[__float_as_int(pkb.x) + col];

    const f32x4 oa = eva + pka.y * w1 + pka.z * w2 + pka.w * w3 + cs;
    const f32x4 ob = evb + pkb.y * w1 + pkb.z * w2 + pkb.w * w3 + cs;

    __builtin_nontemporal_store(oa, &out[((long)ra << LOG2_H4) + col]);
    __builtin_nontemporal_store(ob, &out[((long)rb << LOG2_H4) + col]);
  }
}

extern "C" void kernel_launch(void* const* d_in, const int* in_sizes, int n_in,
                              void* d_out, int out_size, void* d_ws, size_t ws_size,
                              hipStream_t stream) {
  const float* enc     = (const float*)d_in[0]; // [B,P,H]
  const float* pitch   = (const float*)d_in[1]; // [B,T]
  const float* beats   = (const float*)d_in[2]; // [B,T]
  const float* w_pitch = (const float*)d_in[3];
  const float* b_pitch = (const float*)d_in[4];
  const float* w_beats = (const float*)d_in[5];
  const float* b_beats = (const float*)d_in[6];
  const float* w_pos   = (const float*)d_in[7];
  const float* b_pos   = (const float*)d_in[8];
  const int* align     = (const int*)d_in[9];   // [B,T]

  f32x4* packed = (f32x4*)d_ws; // B*T float4 = 2 MB scratch

  scan_idx_kernel<<<B, 256, 0, stream>>>(align, pitch, beats, packed);

  // (B*T)/64 = 2048 blocks, each covering 64 consecutive rows.
  fuse_kernel<<<(B * T) / 64, 256, 0, stream>>>(
      (const f32x4*)enc, packed,
      (const f32x4*)w_pitch, (const f32x4*)b_pitch,
      (const f32x4*)w_beats, (const f32x4*)b_beats,
      (const f32x4*)w_pos, (const f32x4*)b_pos,
      (f32x4*)d_out);
  (void)in_sizes; (void)n_in; (void)out_size; (void)ws_size;
}